// Round 5
// baseline (62.015 us; speedup 1.0000x reference)
//
#include <hip/hip_runtime.h>

// Problem geometry (fixed by the reference file).
constexpr int B = 16;
constexpr int V = 16384;                 // variants per batch
constexpr int G = 20000;                 // genes
constexpr int D = 64;                    // embedding dim
constexpr int NCELLS = B * G;            // 320,000 output cells
constexpr int NROWS  = B * V;            // 262,144 variant rows
constexpr int OVF_MAX = 16384;
constexpr long long OUT_N = (long long)NCELLS * D;   // 20,480,000 floats

// Native vector type accepted by __builtin_nontemporal_load/store.
typedef float f32x4 __attribute__((ext_vector_type(4)));

// ---------------------------- header+spill layout ----------------------------
// ws layout (u32 units):
//   [0, 4*NCELLS)                       headers: {count, r0, r1, r2} per cell
//   [OVF_HDR]                           overflow counter
//   [OVF_LIST, OVF_LIST+2*OVF_MAX)     overflow (cell,row) pairs
//   [SPILL_OFF, SPILL_OFF+NCELLS*SCAP) spill rows (rows 3..3+SCAP-1 per cell)
constexpr int HDR_WORDS = 4 * NCELLS;
constexpr int OVF_HDR   = HDR_WORDS;
constexpr int OVF_LIST  = HDR_WORDS + 1;
constexpr int SPILL_OFF = HDR_WORDS + 1 + 2 * OVF_MAX;

__global__ void ga_zero(uint4* __restrict__ ws4, unsigned int* __restrict__ ws) {
  int stride = gridDim.x * blockDim.x;
  for (int i = blockIdx.x * blockDim.x + threadIdx.x; i < HDR_WORDS / 4; i += stride)
    ws4[i] = make_uint4(0u, 0u, 0u, 0u);
  if (blockIdx.x == 0 && threadIdx.x == 0) ws[OVF_HDR] = 0u;
}

__global__ void ga_build(const int* __restrict__ gene_ids,
                         const int* __restrict__ mask,
                         unsigned int* __restrict__ ws, int scap) {
  int r = blockIdx.x * blockDim.x + threadIdx.x;   // global variant row
  if (r >= NROWS) return;
  if (!mask[r]) return;
  int cell = (r >> 14) * G + gene_ids[r];          // r>>14 == batch
  unsigned int pos = atomicAdd(&ws[cell * 4], 1u);
  if (pos < 3u) {
    ws[cell * 4 + 1 + pos] = (unsigned int)r;
  } else if (pos < 3u + (unsigned int)scap) {
    ws[SPILL_OFF + (size_t)cell * scap + (pos - 3u)] = (unsigned int)r;
  } else {
    unsigned int o = atomicAdd(&ws[OVF_HDR], 1u);
    if (o < (unsigned int)OVF_MAX) {
      ws[OVF_LIST + 2 * o + 0] = (unsigned int)cell;
      ws[OVF_LIST + 2 * o + 1] = (unsigned int)r;
    }
  }
}

__device__ __forceinline__ void fmax4(f32x4& a, f32x4 v) {
  a.x = fmaxf(a.x, v.x);
  a.y = fmaxf(a.y, v.y);
  a.z = fmaxf(a.z, v.z);
  a.w = fmaxf(a.w, v.w);
}

// CPT cells per thread, strided by NCELLS/CPT so each group of 16 consecutive
// threads shares one cell (coalesced 256 B emb reads and out writes).
// The common path (c <= 1) is branch-free: the first-row load is unconditional
// with the row clamped to 0 for empty cells (row 0 stays cache-resident, ~free),
// so all CPT header->emb chains software-pipeline with full MLP.
constexpr int CPT = 8;
__global__ void ga_gather(const f32x4* __restrict__ emb4,
                          const uint4* __restrict__ hdr,
                          const unsigned int* __restrict__ spill,
                          f32x4* __restrict__ out4, int scap) {
  const int STRIDE = NCELLS / CPT;                 // 40,000
  int t = blockIdx.x * blockDim.x + threadIdx.x;
  int cell0 = t >> 4;
  int sub   = t & 15;                              // same sub for all k
  if (cell0 >= STRIDE) return;

  uint4 h[CPT];
#pragma unroll
  for (int k = 0; k < CPT; ++k)
    h[k] = hdr[cell0 + k * STRIDE];

  // Unconditional first-row loads: empty cells read row 0 (broadcast line).
  f32x4 v0[CPT];
#pragma unroll
  for (int k = 0; k < CPT; ++k) {
    unsigned int row = h[k].x ? h[k].y : 0u;
    v0[k] = __builtin_nontemporal_load(&emb4[(size_t)row * 16 + sub]);
  }

#pragma unroll
  for (int k = 0; k < CPT; ++k) {
    int cell = cell0 + k * STRIDE;
    unsigned int c = h[k].x;
    f32x4 acc = v0[k];                             // fold starts at first row
    if (c >= 2u) fmax4(acc, emb4[(size_t)h[k].z * 16 + sub]);
    if (c >= 3u) fmax4(acc, emb4[(size_t)h[k].w * 16 + sub]);
    if (c > 3u) {                                  // rare spill path (~5%)
      int n1 = (int)c - 3; if (n1 > scap) n1 = scap;
      const unsigned int* sp = spill + (size_t)cell * scap;
      for (int j = 0; j < n1; ++j)
        fmax4(acc, emb4[(size_t)sp[j] * 16 + sub]);
    }
    if (c == 0u) acc = (f32x4)(0.f);
    __builtin_nontemporal_store(acc, &out4[(size_t)cell * 16 + sub]);
  }
}

__device__ __forceinline__ void atomic_max_float(float* addr, float val) {
  unsigned int* ua = (unsigned int*)addr;
  unsigned int old = *ua;
  while (__uint_as_float(old) < val) {
    unsigned int assumed = old;
    old = atomicCAS(ua, assumed, __float_as_uint(val));
    if (old == assumed) break;
  }
}

// Drain overflow entries (expected: none — P(cell count > 3+scap) ~ 1e-10).
__global__ void ga_ovf(const f32x4* __restrict__ emb4,
                       const unsigned int* __restrict__ ws,
                       float* __restrict__ out) {
  unsigned int nov = ws[OVF_HDR];
  if (nov > (unsigned int)OVF_MAX) nov = OVF_MAX;
  int total = (int)nov * 16;
  int stride = gridDim.x * blockDim.x;
  for (int u = blockIdx.x * blockDim.x + threadIdx.x; u < total; u += stride) {
    int e = u >> 4, sub = u & 15;
    unsigned int cell = ws[OVF_LIST + 2 * e + 0];
    unsigned int row  = ws[OVF_LIST + 2 * e + 1];
    f32x4 v = emb4[(size_t)row * 16 + sub];
    float* o = out + (size_t)cell * 64 + sub * 4;
    atomic_max_float(o + 0, v.x);
    atomic_max_float(o + 1, v.y);
    atomic_max_float(o + 2, v.z);
    atomic_max_float(o + 3, v.w);
  }
}

// ------------------------- legacy atomic path (ws too small) -----------------
__device__ __forceinline__ unsigned int enc_f32(float f) {
  unsigned int u = __float_as_uint(f);
  return (u & 0x80000000u) ? ~u : (u | 0x80000000u);
}
__device__ __forceinline__ float dec_f32(unsigned int e) {
  unsigned int u = (e & 0x80000000u) ? (e ^ 0x80000000u) : ~e;
  return __uint_as_float(u);
}

__global__ void ga_init(uint4* __restrict__ out4, int n4) {
  int stride = gridDim.x * blockDim.x;
  for (int i = blockIdx.x * blockDim.x + threadIdx.x; i < n4; i += stride)
    out4[i] = make_uint4(0u, 0u, 0u, 0u);
}

__global__ void ga_scatter(const float4* __restrict__ emb4,
                           const int* __restrict__ gene_ids,
                           const int* __restrict__ mask,
                           unsigned int* __restrict__ out) {
  int tid = blockIdx.x * blockDim.x + threadIdx.x;
  int v  = tid >> 4;
  int dq = tid & 15;
  if (!mask[v]) return;
  int g = gene_ids[v];
  int b = v >> 14;
  float4 e = emb4[tid];
  int base = (b * G + g) * D + (dq << 2);
  atomicMax(out + base + 0, enc_f32(e.x));
  atomicMax(out + base + 1, enc_f32(e.y));
  atomicMax(out + base + 2, enc_f32(e.z));
  atomicMax(out + base + 3, enc_f32(e.w));
}

__global__ void ga_finalize(uint4* __restrict__ io4, int n4) {
  int stride = gridDim.x * blockDim.x;
  for (int i = blockIdx.x * blockDim.x + threadIdx.x; i < n4; i += stride) {
    uint4 e = io4[i];
    float4 f;
    f.x = e.x ? dec_f32(e.x) : 0.0f;
    f.y = e.y ? dec_f32(e.y) : 0.0f;
    f.z = e.z ? dec_f32(e.z) : 0.0f;
    f.w = e.w ? dec_f32(e.w) : 0.0f;
    *reinterpret_cast<float4*>(io4 + i) = f;
  }
}

// -----------------------------------------------------------------------------
extern "C" void kernel_launch(void* const* d_in, const int* in_sizes, int n_in,
                              void* d_out, int out_size, void* d_ws, size_t ws_size,
                              hipStream_t stream) {
  const float4* emb4     = (const float4*)d_in[0];   // [B,V,D] f32
  const int*    gene_ids = (const int*)d_in[1];      // [B,V]
  const int*    mask     = (const int*)d_in[2];      // [B,V]

  long long ws_u32 = (long long)(ws_size / 4);
  long long avail  = ws_u32 - (long long)SPILL_OFF;
  int scap = (int)(avail > 0 ? avail / NCELLS : -1);
  if (scap > 13) scap = 13;

  if (scap >= 0) {
    unsigned int* ws = (unsigned int*)d_ws;
    ga_zero<<<1024, 256, 0, stream>>>((uint4*)d_ws, ws);
    ga_build<<<NROWS / 256, 256, 0, stream>>>(gene_ids, mask, ws, scap);
    const int N = (NCELLS / CPT) * 16;               // 640,000 threads
    ga_gather<<<N / 256, 256, 0, stream>>>(
        (const f32x4*)emb4, (const uint4*)d_ws, ws + SPILL_OFF,
        (f32x4*)d_out, scap);
    ga_ovf<<<64, 256, 0, stream>>>((const f32x4*)emb4, ws, (float*)d_out);
  } else {
    // Fallback: direct atomic scatter-max (round-1 passing version).
    unsigned int* out_u = (unsigned int*)d_out;
    const int n4 = (int)(OUT_N / 4);
    ga_init<<<2048, 256, 0, stream>>>((uint4*)d_out, n4);
    ga_scatter<<<(NROWS * 16) / 256, 256, 0, stream>>>(emb4, gene_ids, mask, out_u);
    ga_finalize<<<2048, 256, 0, stream>>>((uint4*)d_out, n4);
  }
}

// Round 6
// 50.352 us; speedup vs baseline: 1.2316x; 1.2316x over previous
//
#include <hip/hip_runtime.h>

// Problem geometry (fixed by the reference file).
constexpr int B = 16;
constexpr int V = 16384;                 // variants per batch
constexpr int G = 20000;                 // genes
constexpr int D = 64;                    // embedding dim
constexpr int NCELLS = B * G;            // 320,000 output cells
constexpr int NROWS  = B * V;            // 262,144 variant rows
constexpr int OVF_MAX = 16384;
constexpr long long OUT_N = (long long)NCELLS * D;   // 20,480,000 floats

// Native vector type accepted by __builtin_nontemporal_load/store.
typedef float f32x4 __attribute__((ext_vector_type(4)));

// ---------------------------- header+spill layout ----------------------------
// ws layout (u32 units):
//   [0, 4*NCELLS)                       headers: {count, r0, r1, r2} per cell
//   [OVF_HDR]                           overflow counter
//   [OVF_LIST, OVF_LIST+2*OVF_MAX)     overflow (cell,row) pairs
//   [SPILL_OFF, SPILL_OFF+NCELLS*SCAP) spill rows (rows 3..3+SCAP-1 per cell)
constexpr int HDR_WORDS = 4 * NCELLS;
constexpr int OVF_HDR   = HDR_WORDS;
constexpr int OVF_LIST  = HDR_WORDS + 1;
constexpr int SPILL_OFF = HDR_WORDS + 1 + 2 * OVF_MAX;

__global__ void ga_zero(uint4* __restrict__ ws4, unsigned int* __restrict__ ws) {
  int stride = gridDim.x * blockDim.x;
  for (int i = blockIdx.x * blockDim.x + threadIdx.x; i < HDR_WORDS / 4; i += stride)
    ws4[i] = make_uint4(0u, 0u, 0u, 0u);
  if (blockIdx.x == 0 && threadIdx.x == 0) ws[OVF_HDR] = 0u;
}

__global__ void ga_build(const int* __restrict__ gene_ids,
                         const int* __restrict__ mask,
                         unsigned int* __restrict__ ws, int scap) {
  int r = blockIdx.x * blockDim.x + threadIdx.x;   // global variant row
  if (r >= NROWS) return;
  if (!mask[r]) return;
  int cell = (r >> 14) * G + gene_ids[r];          // r>>14 == batch
  unsigned int pos = atomicAdd(&ws[cell * 4], 1u);
  if (pos < 3u) {
    ws[cell * 4 + 1 + pos] = (unsigned int)r;
  } else if (pos < 3u + (unsigned int)scap) {
    ws[SPILL_OFF + (size_t)cell * scap + (pos - 3u)] = (unsigned int)r;
  } else {
    unsigned int o = atomicAdd(&ws[OVF_HDR], 1u);
    if (o < (unsigned int)OVF_MAX) {
      ws[OVF_LIST + 2 * o + 0] = (unsigned int)cell;
      ws[OVF_LIST + 2 * o + 1] = (unsigned int)r;
    }
  }
}

__device__ __forceinline__ void fmax4(f32x4& a, f32x4 v) {
  a.x = fmaxf(a.x, v.x);
  a.y = fmaxf(a.y, v.y);
  a.z = fmaxf(a.z, v.z);
  a.w = fmaxf(a.w, v.w);
}

// CPT cells per thread, strided by NCELLS/CPT so each group of 16 consecutive
// threads shares one cell (coalesced 256 B emb reads and out writes).
// Branch-free common path: first-row load is unconditional with the row
// clamped to 0 for empty cells. Loads are NORMAL cached loads — row 0 stays
// resident in each CU's L1, so the 44% empty-cell loads are L1 hits
// (the R5 regression was nt-loads defeating exactly this retention).
constexpr int CPT = 8;
__global__ void ga_gather(const f32x4* __restrict__ emb4,
                          const uint4* __restrict__ hdr,
                          const unsigned int* __restrict__ spill,
                          f32x4* __restrict__ out4, int scap) {
  const int STRIDE = NCELLS / CPT;                 // 40,000
  int t = blockIdx.x * blockDim.x + threadIdx.x;
  int cell0 = t >> 4;
  int sub   = t & 15;                              // same sub for all k
  if (cell0 >= STRIDE) return;

  uint4 h[CPT];
#pragma unroll
  for (int k = 0; k < CPT; ++k)
    h[k] = hdr[cell0 + k * STRIDE];

  // Unconditional first-row loads: empty cells read row 0 (L1-resident line).
  f32x4 v0[CPT];
#pragma unroll
  for (int k = 0; k < CPT; ++k) {
    unsigned int row = h[k].x ? h[k].y : 0u;
    v0[k] = emb4[(size_t)row * 16 + sub];
  }

#pragma unroll
  for (int k = 0; k < CPT; ++k) {
    int cell = cell0 + k * STRIDE;
    unsigned int c = h[k].x;
    f32x4 acc = v0[k];                             // fold starts at first row
    if (c >= 2u) fmax4(acc, emb4[(size_t)h[k].z * 16 + sub]);
    if (c >= 3u) fmax4(acc, emb4[(size_t)h[k].w * 16 + sub]);
    if (c > 3u) {                                  // rare spill path (~5%)
      int n1 = (int)c - 3; if (n1 > scap) n1 = scap;
      const unsigned int* sp = spill + (size_t)cell * scap;
      for (int j = 0; j < n1; ++j)
        fmax4(acc, emb4[(size_t)sp[j] * 16 + sub]);
    }
    if (c == 0u) acc = (f32x4)(0.f);
    __builtin_nontemporal_store(acc, &out4[(size_t)cell * 16 + sub]);
  }
}

__device__ __forceinline__ void atomic_max_float(float* addr, float val) {
  unsigned int* ua = (unsigned int*)addr;
  unsigned int old = *ua;
  while (__uint_as_float(old) < val) {
    unsigned int assumed = old;
    old = atomicCAS(ua, assumed, __float_as_uint(val));
    if (old == assumed) break;
  }
}

// Drain overflow entries (expected: none — P(cell count > 3+scap) ~ 1e-10).
__global__ void ga_ovf(const f32x4* __restrict__ emb4,
                       const unsigned int* __restrict__ ws,
                       float* __restrict__ out) {
  unsigned int nov = ws[OVF_HDR];
  if (nov > (unsigned int)OVF_MAX) nov = OVF_MAX;
  int total = (int)nov * 16;
  int stride = gridDim.x * blockDim.x;
  for (int u = blockIdx.x * blockDim.x + threadIdx.x; u < total; u += stride) {
    int e = u >> 4, sub = u & 15;
    unsigned int cell = ws[OVF_LIST + 2 * e + 0];
    unsigned int row  = ws[OVF_LIST + 2 * e + 1];
    f32x4 v = emb4[(size_t)row * 16 + sub];
    float* o = out + (size_t)cell * 64 + sub * 4;
    atomic_max_float(o + 0, v.x);
    atomic_max_float(o + 1, v.y);
    atomic_max_float(o + 2, v.z);
    atomic_max_float(o + 3, v.w);
  }
}

// ------------------------- legacy atomic path (ws too small) -----------------
__device__ __forceinline__ unsigned int enc_f32(float f) {
  unsigned int u = __float_as_uint(f);
  return (u & 0x80000000u) ? ~u : (u | 0x80000000u);
}
__device__ __forceinline__ float dec_f32(unsigned int e) {
  unsigned int u = (e & 0x80000000u) ? (e ^ 0x80000000u) : ~e;
  return __uint_as_float(u);
}

__global__ void ga_init(uint4* __restrict__ out4, int n4) {
  int stride = gridDim.x * blockDim.x;
  for (int i = blockIdx.x * blockDim.x + threadIdx.x; i < n4; i += stride)
    out4[i] = make_uint4(0u, 0u, 0u, 0u);
}

__global__ void ga_scatter(const float4* __restrict__ emb4,
                           const int* __restrict__ gene_ids,
                           const int* __restrict__ mask,
                           unsigned int* __restrict__ out) {
  int tid = blockIdx.x * blockDim.x + threadIdx.x;
  int v  = tid >> 4;
  int dq = tid & 15;
  if (!mask[v]) return;
  int g = gene_ids[v];
  int b = v >> 14;
  float4 e = emb4[tid];
  int base = (b * G + g) * D + (dq << 2);
  atomicMax(out + base + 0, enc_f32(e.x));
  atomicMax(out + base + 1, enc_f32(e.y));
  atomicMax(out + base + 2, enc_f32(e.z));
  atomicMax(out + base + 3, enc_f32(e.w));
}

__global__ void ga_finalize(uint4* __restrict__ io4, int n4) {
  int stride = gridDim.x * blockDim.x;
  for (int i = blockIdx.x * blockDim.x + threadIdx.x; i < n4; i += stride) {
    uint4 e = io4[i];
    float4 f;
    f.x = e.x ? dec_f32(e.x) : 0.0f;
    f.y = e.y ? dec_f32(e.y) : 0.0f;
    f.z = e.z ? dec_f32(e.z) : 0.0f;
    f.w = e.w ? dec_f32(e.w) : 0.0f;
    *reinterpret_cast<float4*>(io4 + i) = f;
  }
}

// -----------------------------------------------------------------------------
extern "C" void kernel_launch(void* const* d_in, const int* in_sizes, int n_in,
                              void* d_out, int out_size, void* d_ws, size_t ws_size,
                              hipStream_t stream) {
  const float4* emb4     = (const float4*)d_in[0];   // [B,V,D] f32
  const int*    gene_ids = (const int*)d_in[1];      // [B,V]
  const int*    mask     = (const int*)d_in[2];      // [B,V]

  long long ws_u32 = (long long)(ws_size / 4);
  long long avail  = ws_u32 - (long long)SPILL_OFF;
  int scap = (int)(avail > 0 ? avail / NCELLS : -1);
  if (scap > 13) scap = 13;

  if (scap >= 0) {
    unsigned int* ws = (unsigned int*)d_ws;
    ga_zero<<<1024, 256, 0, stream>>>((uint4*)d_ws, ws);
    ga_build<<<NROWS / 256, 256, 0, stream>>>(gene_ids, mask, ws, scap);
    const int N = (NCELLS / CPT) * 16;               // 640,000 threads
    ga_gather<<<N / 256, 256, 0, stream>>>(
        (const f32x4*)emb4, (const uint4*)d_ws, ws + SPILL_OFF,
        (f32x4*)d_out, scap);
    ga_ovf<<<64, 256, 0, stream>>>((const f32x4*)emb4, ws, (float*)d_out);
  } else {
    // Fallback: direct atomic scatter-max (round-1 passing version).
    unsigned int* out_u = (unsigned int*)d_out;
    const int n4 = (int)(OUT_N / 4);
    ga_init<<<2048, 256, 0, stream>>>((uint4*)d_out, n4);
    ga_scatter<<<(NROWS * 16) / 256, 256, 0, stream>>>(emb4, gene_ids, mask, out_u);
    ga_finalize<<<2048, 256, 0, stream>>>((uint4*)d_out, n4);
  }
}

// Round 7
// 49.345 us; speedup vs baseline: 1.2568x; 1.0204x over previous
//
#include <hip/hip_runtime.h>

// Problem geometry (fixed by the reference file).
constexpr int B = 16;
constexpr int V = 16384;                 // variants per batch
constexpr int G = 20000;                 // genes
constexpr int D = 64;                    // embedding dim
constexpr int NCELLS = B * G;            // 320,000 output cells
constexpr int NROWS  = B * V;            // 262,144 variant rows
constexpr int OVF_MAX = 16384;
constexpr long long OUT_N = (long long)NCELLS * D;   // 20,480,000 floats

// Native vector type accepted by __builtin_nontemporal_load/store.
typedef float f32x4 __attribute__((ext_vector_type(4)));

// ---------------------------- header+spill layout ----------------------------
// ws layout (u32 units):
//   [0, 4*NCELLS)                       headers: {count, r0, r1, r2} per cell
//   [OVF_HDR]                           overflow counter
//   [OVF_LIST, OVF_LIST+2*OVF_MAX)     overflow (cell,row) pairs
//   [SPILL_OFF, SPILL_OFF+NCELLS*SCAP) spill rows (rows 3..3+SCAP-1 per cell)
constexpr int HDR_WORDS = 4 * NCELLS;
constexpr int OVF_HDR   = HDR_WORDS;
constexpr int OVF_LIST  = HDR_WORDS + 1;
constexpr int SPILL_OFF = HDR_WORDS + 1 + 2 * OVF_MAX;

__global__ void ga_zero(uint4* __restrict__ ws4, unsigned int* __restrict__ ws) {
  int stride = gridDim.x * blockDim.x;
  for (int i = blockIdx.x * blockDim.x + threadIdx.x; i < HDR_WORDS / 4; i += stride)
    ws4[i] = make_uint4(0u, 0u, 0u, 0u);
  if (blockIdx.x == 0 && threadIdx.x == 0) ws[OVF_HDR] = 0u;
}

__global__ void ga_build(const int* __restrict__ gene_ids,
                         const int* __restrict__ mask,
                         unsigned int* __restrict__ ws, int scap) {
  int r = blockIdx.x * blockDim.x + threadIdx.x;   // global variant row
  if (r >= NROWS) return;
  if (!mask[r]) return;
  int cell = (r >> 14) * G + gene_ids[r];          // r>>14 == batch
  unsigned int pos = atomicAdd(&ws[cell * 4], 1u);
  if (pos < 3u) {
    ws[cell * 4 + 1 + pos] = (unsigned int)r;
  } else if (pos < 3u + (unsigned int)scap) {
    ws[SPILL_OFF + (size_t)cell * scap + (pos - 3u)] = (unsigned int)r;
  } else {
    unsigned int o = atomicAdd(&ws[OVF_HDR], 1u);
    if (o < (unsigned int)OVF_MAX) {
      ws[OVF_LIST + 2 * o + 0] = (unsigned int)cell;
      ws[OVF_LIST + 2 * o + 1] = (unsigned int)r;
    }
  }
}

__device__ __forceinline__ void fmax4(f32x4& a, f32x4 v) {
  a.x = fmaxf(a.x, v.x);
  a.y = fmaxf(a.y, v.y);
  a.z = fmaxf(a.z, v.z);
  a.w = fmaxf(a.w, v.w);
}

// CPT cells per thread, strided by NCELLS/CPT; 16 consecutive threads share one
// cell (coalesced 256 B emb reads and out writes).
// ZERO-BRANCH common path (c <= 3, ~99% of cells): rows 1 and 2 are loaded
// unconditionally with ids clamped to row0 (max(a,a)=a makes duplicates exact
// no-ops; the clamped loads hit the v0 line in L1). Empty cells clamp to
// emb row 0 (L1-resident) and are cndmask'd to zero. All CPT*3 loads issue
// without intervening control flow -> full memory-level parallelism.
constexpr int CPT = 8;
__global__ void ga_gather(const f32x4* __restrict__ emb4,
                          const uint4* __restrict__ hdr,
                          const unsigned int* __restrict__ spill,
                          f32x4* __restrict__ out4, int scap) {
  const int STRIDE = NCELLS / CPT;                 // 40,000
  int t = blockIdx.x * blockDim.x + threadIdx.x;
  int cell0 = t >> 4;
  int sub   = t & 15;                              // same sub for all k
  if (cell0 >= STRIDE) return;

  uint4 h[CPT];
#pragma unroll
  for (int k = 0; k < CPT; ++k)
    h[k] = hdr[cell0 + k * STRIDE];

  f32x4 v0[CPT], v1[CPT], v2[CPT];
#pragma unroll
  for (int k = 0; k < CPT; ++k) {
    unsigned int c  = h[k].x;
    unsigned int r0 = c ? h[k].y : 0u;             // empty -> row 0 (L1 hit)
    unsigned int r1 = (c >= 2u) ? h[k].z : r0;     // clamp -> same line as v0
    unsigned int r2 = (c >= 3u) ? h[k].w : r0;
    v0[k] = emb4[(size_t)r0 * 16 + sub];
    v1[k] = emb4[(size_t)r1 * 16 + sub];
    v2[k] = emb4[(size_t)r2 * 16 + sub];
  }

#pragma unroll
  for (int k = 0; k < CPT; ++k) {
    int cell = cell0 + k * STRIDE;
    unsigned int c = h[k].x;
    f32x4 acc = v0[k];
    fmax4(acc, v1[k]);                             // duplicate -> no-op
    fmax4(acc, v2[k]);
    if (c > 3u) {                                  // rare spill path (~1%)
      int n1 = (int)c - 3; if (n1 > scap) n1 = scap;
      const unsigned int* sp = spill + (size_t)cell * scap;
      for (int j = 0; j < n1; ++j)
        fmax4(acc, emb4[(size_t)sp[j] * 16 + sub]);
    }
    acc.x = c ? acc.x : 0.f;                       // cndmask, no branch
    acc.y = c ? acc.y : 0.f;
    acc.z = c ? acc.z : 0.f;
    acc.w = c ? acc.w : 0.f;
    __builtin_nontemporal_store(acc, &out4[(size_t)cell * 16 + sub]);
  }
}

__device__ __forceinline__ void atomic_max_float(float* addr, float val) {
  unsigned int* ua = (unsigned int*)addr;
  unsigned int old = *ua;
  while (__uint_as_float(old) < val) {
    unsigned int assumed = old;
    old = atomicCAS(ua, assumed, __float_as_uint(val));
    if (old == assumed) break;
  }
}

// Drain overflow entries (expected: none — P(cell count > 3+scap) ~ 1e-10).
__global__ void ga_ovf(const f32x4* __restrict__ emb4,
                       const unsigned int* __restrict__ ws,
                       float* __restrict__ out) {
  unsigned int nov = ws[OVF_HDR];
  if (nov > (unsigned int)OVF_MAX) nov = OVF_MAX;
  int total = (int)nov * 16;
  int stride = gridDim.x * blockDim.x;
  for (int u = blockIdx.x * blockDim.x + threadIdx.x; u < total; u += stride) {
    int e = u >> 4, sub = u & 15;
    unsigned int cell = ws[OVF_LIST + 2 * e + 0];
    unsigned int row  = ws[OVF_LIST + 2 * e + 1];
    f32x4 v = emb4[(size_t)row * 16 + sub];
    float* o = out + (size_t)cell * 64 + sub * 4;
    atomic_max_float(o + 0, v.x);
    atomic_max_float(o + 1, v.y);
    atomic_max_float(o + 2, v.z);
    atomic_max_float(o + 3, v.w);
  }
}

// ------------------------- legacy atomic path (ws too small) -----------------
__device__ __forceinline__ unsigned int enc_f32(float f) {
  unsigned int u = __float_as_uint(f);
  return (u & 0x80000000u) ? ~u : (u | 0x80000000u);
}
__device__ __forceinline__ float dec_f32(unsigned int e) {
  unsigned int u = (e & 0x80000000u) ? (e ^ 0x80000000u) : ~e;
  return __uint_as_float(u);
}

__global__ void ga_init(uint4* __restrict__ out4, int n4) {
  int stride = gridDim.x * blockDim.x;
  for (int i = blockIdx.x * blockDim.x + threadIdx.x; i < n4; i += stride)
    out4[i] = make_uint4(0u, 0u, 0u, 0u);
}

__global__ void ga_scatter(const float4* __restrict__ emb4,
                           const int* __restrict__ gene_ids,
                           const int* __restrict__ mask,
                           unsigned int* __restrict__ out) {
  int tid = blockIdx.x * blockDim.x + threadIdx.x;
  int v  = tid >> 4;
  int dq = tid & 15;
  if (!mask[v]) return;
  int g = gene_ids[v];
  int b = v >> 14;
  float4 e = emb4[tid];
  int base = (b * G + g) * D + (dq << 2);
  atomicMax(out + base + 0, enc_f32(e.x));
  atomicMax(out + base + 1, enc_f32(e.y));
  atomicMax(out + base + 2, enc_f32(e.z));
  atomicMax(out + base + 3, enc_f32(e.w));
}

__global__ void ga_finalize(uint4* __restrict__ io4, int n4) {
  int stride = gridDim.x * blockDim.x;
  for (int i = blockIdx.x * blockDim.x + threadIdx.x; i < n4; i += stride) {
    uint4 e = io4[i];
    float4 f;
    f.x = e.x ? dec_f32(e.x) : 0.0f;
    f.y = e.y ? dec_f32(e.y) : 0.0f;
    f.z = e.z ? dec_f32(e.z) : 0.0f;
    f.w = e.w ? dec_f32(e.w) : 0.0f;
    *reinterpret_cast<float4*>(io4 + i) = f;
  }
}

// -----------------------------------------------------------------------------
extern "C" void kernel_launch(void* const* d_in, const int* in_sizes, int n_in,
                              void* d_out, int out_size, void* d_ws, size_t ws_size,
                              hipStream_t stream) {
  const float4* emb4     = (const float4*)d_in[0];   // [B,V,D] f32
  const int*    gene_ids = (const int*)d_in[1];      // [B,V]
  const int*    mask     = (const int*)d_in[2];      // [B,V]

  long long ws_u32 = (long long)(ws_size / 4);
  long long avail  = ws_u32 - (long long)SPILL_OFF;
  int scap = (int)(avail > 0 ? avail / NCELLS : -1);
  if (scap > 13) scap = 13;

  if (scap >= 0) {
    unsigned int* ws = (unsigned int*)d_ws;
    ga_zero<<<1024, 256, 0, stream>>>((uint4*)d_ws, ws);
    ga_build<<<NROWS / 256, 256, 0, stream>>>(gene_ids, mask, ws, scap);
    const int N = (NCELLS / CPT) * 16;               // 640,000 threads
    ga_gather<<<N / 256, 256, 0, stream>>>(
        (const f32x4*)emb4, (const uint4*)d_ws, ws + SPILL_OFF,
        (f32x4*)d_out, scap);
    ga_ovf<<<64, 256, 0, stream>>>((const f32x4*)emb4, ws, (float*)d_out);
  } else {
    // Fallback: direct atomic scatter-max (round-1 passing version).
    unsigned int* out_u = (unsigned int*)d_out;
    const int n4 = (int)(OUT_N / 4);
    ga_init<<<2048, 256, 0, stream>>>((uint4*)d_out, n4);
    ga_scatter<<<(NROWS * 16) / 256, 256, 0, stream>>>(emb4, gene_ids, mask, out_u);
    ga_finalize<<<2048, 256, 0, stream>>>((uint4*)d_out, n4);
  }
}